// Round 9
// baseline (165.361 us; speedup 1.0000x reference)
//
#include <hip/hip_runtime.h>
#include <hip/hip_fp16.h>
#include <math.h>

// Problem constants
#define HID   1024
#define NHEAD 16
#define HD    64
#define NB    64
#define MAXS  2048
#define CHUNK 256
#define NCH   (MAXS / CHUNK)          // 8
#define PS    68                      // floats per (chunk,b,h) partial record

// Non-temporal float4 load: skips cache retention on the streamed-once KV
// read. Measured: KV stream 4.5 -> 6.4 TB/s (R5/R7/R8 triple).
typedef float f4v __attribute__((ext_vector_type(4)));
__device__ __forceinline__ float4 ntload4(const float* p) {
    f4v v = __builtin_nontemporal_load((const f4v*)p);
    return make_float4(v.x, v.y, v.z, v.w);
}

// ---------------------------------------------------------------------------
// Kernel 1: fused projections (unchanged — W read exactly once)
// ---------------------------------------------------------------------------
__global__ __launch_bounds__(1024) void proj_kernel(
    const float* __restrict__ seq, const float* __restrict__ cand,
    const float* __restrict__ Wqkv, const float* __restrict__ bqkv,
    const float* __restrict__ Wc,   const float* __restrict__ bcv,
    float* __restrict__ out /* [4096][64] col-major */)
{
    const int tid  = threadIdx.x;
    const int wv   = __builtin_amdgcn_readfirstlane(tid >> 6);
    const int lane = tid & 63;
    const int c0   = blockIdx.x * 16;
    const bool is_qkv = (c0 < 3072);
    const float* __restrict__ src  = is_qkv ? seq  : cand;
    const float* __restrict__ W    = is_qkv ? Wqkv : Wc;
    const float* __restrict__ bias = is_qkv ? bqkv : bcv;
    const int ldw = is_qkv ? 3072 : 1024;
    const int cb  = is_qkv ? c0 : (c0 - 3072);
    const int k0  = wv * 64;

    float acc[16];
    #pragma unroll
    for (int j = 0; j < 16; ++j) acc[j] = 0.f;

    const float4* sp = (const float4*)(src + lane * HID + k0);
    for (int kc = 0; kc < 16; ++kc) {
        float4 s4 = sp[kc];
        const float* wb = W + (size_t)(k0 + kc * 4) * ldw + cb;
        #pragma unroll
        for (int t = 0; t < 4; ++t) {
            float sv = (t == 0) ? s4.x : (t == 1) ? s4.y : (t == 2) ? s4.z : s4.w;
            const float4* wr = (const float4*)(wb + (size_t)t * ldw);
            #pragma unroll
            for (int j = 0; j < 4; ++j) {
                float4 w4 = wr[j];
                acc[4*j+0] = fmaf(sv, w4.x, acc[4*j+0]);
                acc[4*j+1] = fmaf(sv, w4.y, acc[4*j+1]);
                acc[4*j+2] = fmaf(sv, w4.z, acc[4*j+2]);
                acc[4*j+3] = fmaf(sv, w4.w, acc[4*j+3]);
            }
        }
    }

    __shared__ float red[16][16][64];
    #pragma unroll
    for (int j = 0; j < 16; ++j) red[wv][j][lane] = acc[j];
    __syncthreads();

    {
        const int j = tid >> 6, b = tid & 63;
        float s = 0.f;
        #pragma unroll
        for (int w = 0; w < 16; ++w) s += red[w][j][b];
        out[(c0 + j) * 64 + b] = s + bias[cb + j];
    }
}

// ---------------------------------------------------------------------------
// Kernel 2: TWO-PHASE chunked attention partials with NON-TEMPORAL k/v
// loads (R8 kernel, unchanged — measured at 6.4 TB/s, read roofline).
// ---------------------------------------------------------------------------
__global__ __launch_bounds__(256) void attn_part_kernel(
    const float* __restrict__ proj, const float* __restrict__ k_cache,
    const float* __restrict__ v_cache, const int* __restrict__ seqlens,
    float* __restrict__ part)
{
    const int idx = blockIdx.x;
    const int c  = idx >> 10;          // chunk slowest: early blocks all valid
    const int bh = idx & 1023;
    const int b  = bh >> 4;
    const int h  = bh & 15;
    const int L  = seqlens[b];
    const int s0 = c << 8;
    if (s0 > L) return;

    const int tid = threadIdx.x;
    const int grp = tid >> 4;
    const int gl  = tid & 15;
    const bool has_new = (L < s0 + CHUNK);

    __shared__ float lq[64], lk[64], lv[64];
    __shared__ float sm_m[16], sm_l[16];
    __shared__ float sm_o[16][64];

    if (tid < 64) {                    // wave 0: q
        lq[tid] = proj[(h * 192 + tid) * 64 + b];
    } else if (tid < 128) {            // wave 1: normalized + fp16-rounded new k
        if (has_new) {
            int d = tid - 64;
            float kr = proj[(h * 192 + 64 + d) * 64 + b];
            float ss = kr * kr;
            #pragma unroll
            for (int m = 1; m < 64; m <<= 1) ss += __shfl_xor(ss, m);
            float kn = kr / sqrtf(ss);
            lk[d] = __half2float(__float2half_rn(kn));
        }
    } else if (tid < 192) {            // wave 2: new v
        if (has_new) {
            int d = tid - 128;
            lv[d] = proj[(h * 192 + 128 + d) * 64 + b];
        }
    }
    __syncthreads();

    const float4 q4 = ((const float4*)lq)[gl];
    const size_t base0 = (((size_t)b * MAXS) * NHEAD + h) * HD;

    float sc[16];
    float m, l;
    float4 o = make_float4(0.f, 0.f, 0.f, 0.f);

    if (!has_new) {
        #pragma unroll
        for (int t = 0; t < 16; ++t) {
            const int s = s0 + grp + t * 16;
            float4 k4 = ntload4(k_cache + base0 + (size_t)s * (NHEAD * HD) + gl * 4);
            float d = fmaf(k4.x, q4.x, fmaf(k4.y, q4.y, fmaf(k4.z, q4.z, k4.w * q4.w)));
            d += __shfl_xor(d, 1); d += __shfl_xor(d, 2);
            d += __shfl_xor(d, 4); d += __shfl_xor(d, 8);
            sc[t] = d;
        }
        m = sc[0];
        #pragma unroll
        for (int t = 1; t < 16; ++t) m = fmaxf(m, sc[t]);
        l = 0.f;
        #pragma unroll
        for (int t = 0; t < 16; ++t) { float p = __expf(sc[t] - m); sc[t] = p; l += p; }
        #pragma unroll
        for (int t = 0; t < 16; ++t) {
            const int s = s0 + grp + t * 16;
            float4 v4 = ntload4(v_cache + base0 + (size_t)s * (NHEAD * HD) + gl * 4);
            o.x = fmaf(sc[t], v4.x, o.x);
            o.y = fmaf(sc[t], v4.y, o.y);
            o.z = fmaf(sc[t], v4.z, o.z);
            o.w = fmaf(sc[t], v4.w, o.w);
        }
    } else {
        #pragma unroll
        for (int t = 0; t < 16; ++t) {
            const int s = s0 + grp + t * 16;
            float4 k4 = make_float4(0.f, 0.f, 0.f, 0.f);
            if (s < L)       k4 = ntload4(k_cache + base0 + (size_t)s * (NHEAD * HD) + gl * 4);
            else if (s == L) k4 = ((const float4*)lk)[gl];
            float d = fmaf(k4.x, q4.x, fmaf(k4.y, q4.y, fmaf(k4.z, q4.z, k4.w * q4.w)));
            d += __shfl_xor(d, 1); d += __shfl_xor(d, 2);
            d += __shfl_xor(d, 4); d += __shfl_xor(d, 8);
            sc[t] = (s <= L) ? d : -INFINITY;
        }
        m = sc[0];
        #pragma unroll
        for (int t = 1; t < 16; ++t) m = fmaxf(m, sc[t]);
        // NaN guard: empty group -> m = -inf; subtract 0 so exp(-inf) = 0.
        const float mm = (m == -INFINITY) ? 0.f : m;
        l = 0.f;
        #pragma unroll
        for (int t = 0; t < 16; ++t) { float p = __expf(sc[t] - mm); sc[t] = p; l += p; }
        #pragma unroll
        for (int t = 0; t < 16; ++t) {
            const int s = s0 + grp + t * 16;
            float4 v4 = make_float4(0.f, 0.f, 0.f, 0.f);
            if (s < L)       v4 = ntload4(v_cache + base0 + (size_t)s * (NHEAD * HD) + gl * 4);
            else if (s == L) v4 = ((const float4*)lv)[gl];
            o.x = fmaf(sc[t], v4.x, o.x);
            o.y = fmaf(sc[t], v4.y, o.y);
            o.z = fmaf(sc[t], v4.z, o.z);
            o.w = fmaf(sc[t], v4.w, o.w);
        }
    }

    if (gl == 0) { sm_m[grp] = m; sm_l[grp] = l; }
    ((float4*)sm_o[grp])[gl] = o;
    __syncthreads();

    if (tid < 64) {
        float M = -INFINITY;
        #pragma unroll
        for (int g = 0; g < 16; ++g) M = fmaxf(M, sm_m[g]);
        float li = 0.f, oi = 0.f;
        #pragma unroll
        for (int g = 0; g < 16; ++g) {
            float w = __expf(sm_m[g] - M);   // empty group: exp(-inf - M) = 0
            li += w * sm_l[g];
            oi += w * sm_o[g][tid];
        }
        float* pb = part + (size_t)(c * 1024 + bh) * PS;
        pb[tid] = oi;
        if (tid == 0) { pb[64] = M; pb[65] = li; }
    }
}

// ---------------------------------------------------------------------------
// Kernel 3: FUSED merge + Wo-GEMV + dual LayerNorm. One block per batch b.
//   Phase A (merge): thread (h = tid>>6, d = tid&63) merges <=8 chunk
//     partials -> attn row b (1024 floats) in LDS.
//   Phase B (wo): 4-way k-split x 256 col-groups of 4 (float4 Wo loads);
//     block streams the full 4 MB Wo (8 blocks/XCD -> L2-resident).
//   Phase C (ln): px stays in registers; block-wide reduce; write both outs.
// Removes 2 kernel launches (~13 us each) and the postx HBM round-trip.
// ---------------------------------------------------------------------------
__global__ __launch_bounds__(1024) void post_kernel(
    const float* __restrict__ proj, const float* __restrict__ part,
    const int* __restrict__ seqlens, const float* __restrict__ Wo,
    const float* __restrict__ bo, const float* __restrict__ seq,
    const float* __restrict__ gamma, const float* __restrict__ beta,
    float* __restrict__ out)
{
    const int b   = blockIdx.x;
    const int tid = threadIdx.x;
    const int nch = (seqlens[b] >> 8) + 1;

    __shared__ float attn_row[1024];          // [h*64+d]
    __shared__ float red[4][4][256];          // [ks][j][cg]
    __shared__ float rsm[16][4];

    // ---- Phase A: merge ----
    {
        const int h = tid >> 6, d = tid & 63;
        float M = -INFINITY, l = 0.f, o = 0.f;
        for (int c = 0; c < nch; ++c) {
            const float* pb = part + (size_t)(c * 1024 + b * 16 + h) * PS;
            float mc = pb[64], lc = pb[65];
            float Mn = fmaxf(M, mc);
            float f = __expf(M - Mn);         // first iter: exp(-inf) = 0
            float w = __expf(mc - Mn);
            o = o * f + w * pb[d];
            l = l * f + w * lc;
            M = Mn;
        }
        attn_row[h * 64 + d] = o / l;
    }
    __syncthreads();

    // ---- Phase B: postx[b][:] = attn_row @ Wo (+bo later) ----
    {
        const int cg = tid & 255;             // col group: cols cg*4..cg*4+3
        const int ks = tid >> 8;              // k-slice: rows ks*256..+255
        float4 a = make_float4(0.f, 0.f, 0.f, 0.f);
        const float* wp = Wo + (size_t)(ks * 256) * 1024 + cg * 4;
        #pragma unroll 4
        for (int k = 0; k < 256; ++k) {
            float av = attn_row[ks * 256 + k];          // wave-uniform broadcast
            float4 w4 = *(const float4*)(wp + (size_t)k * 1024);
            a.x = fmaf(av, w4.x, a.x);
            a.y = fmaf(av, w4.y, a.y);
            a.z = fmaf(av, w4.z, a.z);
            a.w = fmaf(av, w4.w, a.w);
        }
        red[ks][0][cg] = a.x; red[ks][1][cg] = a.y;
        red[ks][2][cg] = a.z; red[ks][3][cg] = a.w;
    }
    __syncthreads();

    // ---- Phase C: dual LayerNorm; thread tid = column c ----
    const int c = tid;
    float px = red[0][c & 3][c >> 2] + red[1][c & 3][c >> 2]
             + red[2][c & 3][c >> 2] + red[3][c & 3][c >> 2] + bo[c];
    float sv = seq[b * HID + c];
    float cd = proj[(3072 + c) * 64 + b];     // cand projection (col-major)
    float x1 = sv + px, x2 = px + cd;

    float s1 = x1, q1 = x1 * x1, s2 = x2, q2 = x2 * x2;
    #pragma unroll
    for (int m = 1; m < 64; m <<= 1) {
        s1 += __shfl_xor(s1, m); q1 += __shfl_xor(q1, m);
        s2 += __shfl_xor(s2, m); q2 += __shfl_xor(q2, m);
    }
    const int wv = tid >> 6, lane = tid & 63;
    if (lane == 0) { rsm[wv][0] = s1; rsm[wv][1] = q1; rsm[wv][2] = s2; rsm[wv][3] = q2; }
    __syncthreads();

    float S1 = 0.f, Q1 = 0.f, S2 = 0.f, Q2 = 0.f;
    #pragma unroll
    for (int w = 0; w < 16; ++w) {
        S1 += rsm[w][0]; Q1 += rsm[w][1]; S2 += rsm[w][2]; Q2 += rsm[w][3];
    }
    const float inv = 1.f / 1024.f;
    float mu1 = S1 * inv, v1 = Q1 * inv - mu1 * mu1;
    float mu2 = S2 * inv, v2 = Q2 * inv - mu2 * mu2;
    float r1 = rsqrtf(v1 + 1e-5f);
    float r2 = rsqrtf(v2 + 1e-5f);

    float g = gamma[c], be = beta[c];
    out[b * HID + c]            = (x1 - mu1) * r1 * g + be;   // seq_out
    out[NB * HID + b * HID + c] = (x2 - mu2) * r2 * g + be;   // candidate_out
}

// ---------------------------------------------------------------------------
extern "C" void kernel_launch(void* const* d_in, const int* in_sizes, int n_in,
                              void* d_out, int out_size, void* d_ws, size_t ws_size,
                              hipStream_t stream) {
    const float* seq      = (const float*)d_in[0];
    const float* cand     = (const float*)d_in[1];
    const float* k_cache  = (const float*)d_in[2];
    const float* v_cache  = (const float*)d_in[3];
    const int*   seqlens  = (const int*)  d_in[4];
    const float* Wqkv     = (const float*)d_in[5];
    const float* bqkv     = (const float*)d_in[6];
    const float* Wc       = (const float*)d_in[7];
    const float* bcv      = (const float*)d_in[8];
    const float* Wo       = (const float*)d_in[9];
    const float* bo       = (const float*)d_in[10];
    const float* gamma    = (const float*)d_in[11];
    const float* beta     = (const float*)d_in[12];
    float* out = (float*)d_out;

    float* ws    = (float*)d_ws;
    float* proj  = ws;                         // [4096][64] = 262144 f
    float* part  = proj + 4096 * 64;           // [8*1024][PS] = 557056 f

    proj_kernel     <<<256, 1024, 0, stream>>>(seq, cand, Wqkv, bqkv, Wc, bcv, proj);
    attn_part_kernel<<<NCH * 1024, 256, 0, stream>>>(proj, k_cache, v_cache, seqlens, part);
    post_kernel     <<<NB, 1024, 0, stream>>>(proj, part, seqlens, Wo, bo, seq, gamma, beta, out);
}

// Round 10
// 163.350 us; speedup vs baseline: 1.0123x; 1.0123x over previous
//
#include <hip/hip_runtime.h>
#include <hip/hip_fp16.h>
#include <math.h>

// Problem constants
#define HID   1024
#define NHEAD 16
#define HD    64
#define NB    64
#define MAXS  2048
#define CHUNK 256
#define NCH   (MAXS / CHUNK)          // 8
#define PS    68                      // floats per (chunk,b,h) partial record

// Non-temporal float4 load: skips cache retention on the streamed-once KV
// read. Measured: KV stream 4.5 -> 6.4 TB/s (R5/R7/R8 triple).
typedef float f4v __attribute__((ext_vector_type(4)));
__device__ __forceinline__ float4 ntload4(const float* p) {
    f4v v = __builtin_nontemporal_load((const f4v*)p);
    return make_float4(v.x, v.y, v.z, v.w);
}

// ---------------------------------------------------------------------------
// Kernel 1: fused projections (R8 version)
// ---------------------------------------------------------------------------
__global__ __launch_bounds__(1024) void proj_kernel(
    const float* __restrict__ seq, const float* __restrict__ cand,
    const float* __restrict__ Wqkv, const float* __restrict__ bqkv,
    const float* __restrict__ Wc,   const float* __restrict__ bcv,
    float* __restrict__ out /* [4096][64] col-major */)
{
    const int tid  = threadIdx.x;
    const int wv   = __builtin_amdgcn_readfirstlane(tid >> 6);
    const int lane = tid & 63;
    const int c0   = blockIdx.x * 16;
    const bool is_qkv = (c0 < 3072);
    const float* __restrict__ src  = is_qkv ? seq  : cand;
    const float* __restrict__ W    = is_qkv ? Wqkv : Wc;
    const float* __restrict__ bias = is_qkv ? bqkv : bcv;
    const int ldw = is_qkv ? 3072 : 1024;
    const int cb  = is_qkv ? c0 : (c0 - 3072);
    const int k0  = wv * 64;

    float acc[16];
    #pragma unroll
    for (int j = 0; j < 16; ++j) acc[j] = 0.f;

    const float4* sp = (const float4*)(src + lane * HID + k0);
    for (int kc = 0; kc < 16; ++kc) {
        float4 s4 = sp[kc];
        const float* wb = W + (size_t)(k0 + kc * 4) * ldw + cb;
        #pragma unroll
        for (int t = 0; t < 4; ++t) {
            float sv = (t == 0) ? s4.x : (t == 1) ? s4.y : (t == 2) ? s4.z : s4.w;
            const float4* wr = (const float4*)(wb + (size_t)t * ldw);
            #pragma unroll
            for (int j = 0; j < 4; ++j) {
                float4 w4 = wr[j];
                acc[4*j+0] = fmaf(sv, w4.x, acc[4*j+0]);
                acc[4*j+1] = fmaf(sv, w4.y, acc[4*j+1]);
                acc[4*j+2] = fmaf(sv, w4.z, acc[4*j+2]);
                acc[4*j+3] = fmaf(sv, w4.w, acc[4*j+3]);
            }
        }
    }

    __shared__ float red[16][16][64];
    #pragma unroll
    for (int j = 0; j < 16; ++j) red[wv][j][lane] = acc[j];
    __syncthreads();

    {
        const int j = tid >> 6, b = tid & 63;
        float s = 0.f;
        #pragma unroll
        for (int w = 0; w < 16; ++w) s += red[w][j][b];
        out[(c0 + j) * 64 + b] = s + bias[cb + j];
    }
}

// ---------------------------------------------------------------------------
// Kernel 2: TWO-PHASE chunked attention partials, nt loads (R8, unchanged —
// measured 6.4 TB/s, read roofline).
// ---------------------------------------------------------------------------
__global__ __launch_bounds__(256) void attn_part_kernel(
    const float* __restrict__ proj, const float* __restrict__ k_cache,
    const float* __restrict__ v_cache, const int* __restrict__ seqlens,
    float* __restrict__ part)
{
    const int idx = blockIdx.x;
    const int c  = idx >> 10;
    const int bh = idx & 1023;
    const int b  = bh >> 4;
    const int h  = bh & 15;
    const int L  = seqlens[b];
    const int s0 = c << 8;
    if (s0 > L) return;

    const int tid = threadIdx.x;
    const int grp = tid >> 4;
    const int gl  = tid & 15;
    const bool has_new = (L < s0 + CHUNK);

    __shared__ float lq[64], lk[64], lv[64];
    __shared__ float sm_m[16], sm_l[16];
    __shared__ float sm_o[16][64];

    if (tid < 64) {
        lq[tid] = proj[(h * 192 + tid) * 64 + b];
    } else if (tid < 128) {
        if (has_new) {
            int d = tid - 64;
            float kr = proj[(h * 192 + 64 + d) * 64 + b];
            float ss = kr * kr;
            #pragma unroll
            for (int m = 1; m < 64; m <<= 1) ss += __shfl_xor(ss, m);
            float kn = kr / sqrtf(ss);
            lk[d] = __half2float(__float2half_rn(kn));
        }
    } else if (tid < 192) {
        if (has_new) {
            int d = tid - 128;
            lv[d] = proj[(h * 192 + 128 + d) * 64 + b];
        }
    }
    __syncthreads();

    const float4 q4 = ((const float4*)lq)[gl];
    const size_t base0 = (((size_t)b * MAXS) * NHEAD + h) * HD;

    float sc[16];
    float m, l;
    float4 o = make_float4(0.f, 0.f, 0.f, 0.f);

    if (!has_new) {
        #pragma unroll
        for (int t = 0; t < 16; ++t) {
            const int s = s0 + grp + t * 16;
            float4 k4 = ntload4(k_cache + base0 + (size_t)s * (NHEAD * HD) + gl * 4);
            float d = fmaf(k4.x, q4.x, fmaf(k4.y, q4.y, fmaf(k4.z, q4.z, k4.w * q4.w)));
            d += __shfl_xor(d, 1); d += __shfl_xor(d, 2);
            d += __shfl_xor(d, 4); d += __shfl_xor(d, 8);
            sc[t] = d;
        }
        m = sc[0];
        #pragma unroll
        for (int t = 1; t < 16; ++t) m = fmaxf(m, sc[t]);
        l = 0.f;
        #pragma unroll
        for (int t = 0; t < 16; ++t) { float p = __expf(sc[t] - m); sc[t] = p; l += p; }
        #pragma unroll
        for (int t = 0; t < 16; ++t) {
            const int s = s0 + grp + t * 16;
            float4 v4 = ntload4(v_cache + base0 + (size_t)s * (NHEAD * HD) + gl * 4);
            o.x = fmaf(sc[t], v4.x, o.x);
            o.y = fmaf(sc[t], v4.y, o.y);
            o.z = fmaf(sc[t], v4.z, o.z);
            o.w = fmaf(sc[t], v4.w, o.w);
        }
    } else {
        #pragma unroll
        for (int t = 0; t < 16; ++t) {
            const int s = s0 + grp + t * 16;
            float4 k4 = make_float4(0.f, 0.f, 0.f, 0.f);
            if (s < L)       k4 = ntload4(k_cache + base0 + (size_t)s * (NHEAD * HD) + gl * 4);
            else if (s == L) k4 = ((const float4*)lk)[gl];
            float d = fmaf(k4.x, q4.x, fmaf(k4.y, q4.y, fmaf(k4.z, q4.z, k4.w * q4.w)));
            d += __shfl_xor(d, 1); d += __shfl_xor(d, 2);
            d += __shfl_xor(d, 4); d += __shfl_xor(d, 8);
            sc[t] = (s <= L) ? d : -INFINITY;
        }
        m = sc[0];
        #pragma unroll
        for (int t = 1; t < 16; ++t) m = fmaxf(m, sc[t]);
        const float mm = (m == -INFINITY) ? 0.f : m;   // NaN guard (empty group)
        l = 0.f;
        #pragma unroll
        for (int t = 0; t < 16; ++t) { float p = __expf(sc[t] - mm); sc[t] = p; l += p; }
        #pragma unroll
        for (int t = 0; t < 16; ++t) {
            const int s = s0 + grp + t * 16;
            float4 v4 = make_float4(0.f, 0.f, 0.f, 0.f);
            if (s < L)       v4 = ntload4(v_cache + base0 + (size_t)s * (NHEAD * HD) + gl * 4);
            else if (s == L) v4 = ((const float4*)lv)[gl];
            o.x = fmaf(sc[t], v4.x, o.x);
            o.y = fmaf(sc[t], v4.y, o.y);
            o.z = fmaf(sc[t], v4.z, o.z);
            o.w = fmaf(sc[t], v4.w, o.w);
        }
    }

    if (gl == 0) { sm_m[grp] = m; sm_l[grp] = l; }
    ((float4*)sm_o[grp])[gl] = o;
    __syncthreads();

    if (tid < 64) {
        float M = -INFINITY;
        #pragma unroll
        for (int g = 0; g < 16; ++g) M = fmaxf(M, sm_m[g]);
        float li = 0.f, oi = 0.f;
        #pragma unroll
        for (int g = 0; g < 16; ++g) {
            float w = __expf(sm_m[g] - M);
            li += w * sm_l[g];
            oi += w * sm_o[g][tid];
        }
        float* pb = part + (size_t)(c * 1024 + bh) * PS;
        pb[tid] = oi;
        if (tid == 0) { pb[64] = M; pb[65] = li; }
    }
}

// ---------------------------------------------------------------------------
// Kernel 3: merge <=8 chunk partials per (b,h). 1024 blocks x 64 threads.
// ---------------------------------------------------------------------------
__global__ __launch_bounds__(64) void attn_merge_kernel(
    const float* __restrict__ part, const int* __restrict__ seqlens,
    float* __restrict__ attn_out /* [1024][64] col-major */)
{
    const int bh = blockIdx.x;
    const int b  = bh >> 4;
    const int h  = bh & 15;
    const int d  = threadIdx.x;
    const int nch = (seqlens[b] >> 8) + 1;

    float M = -INFINITY, l = 0.f, o = 0.f;
    for (int c = 0; c < nch; ++c) {
        const float* pb = part + (size_t)(c * 1024 + bh) * PS;
        float mc = pb[64], lc = pb[65];
        float Mn = fmaxf(M, mc);
        float f = __expf(M - Mn);
        float w = __expf(mc - Mn);
        o = o * f + w * pb[d];
        l = l * f + w * lc;
        M = Mn;
    }
    attn_out[(h * 64 + d) * 64 + b] = o / l;
}

// ---------------------------------------------------------------------------
// Kernel 4: postx = attn @ Wo + bo (R8 version — Wo read exactly once)
// ---------------------------------------------------------------------------
__global__ __launch_bounds__(1024) void wo_kernel(
    const float* __restrict__ attn_s, const float* __restrict__ Wo,
    const float* __restrict__ bo, float* __restrict__ postx /* [1024][64] */)
{
    const int tid  = threadIdx.x;
    const int wv   = __builtin_amdgcn_readfirstlane(tid >> 6);
    const int lane = tid & 63;
    const int c0   = blockIdx.x * 8;
    const int k0   = wv * 64;

    float acc[8];
    #pragma unroll
    for (int j = 0; j < 8; ++j) acc[j] = 0.f;

    for (int k = 0; k < 64; ++k) {
        float sv = attn_s[(k0 + k) * 64 + lane];
        const float4* wr = (const float4*)(Wo + (size_t)(k0 + k) * 1024 + c0);
        float4 w0 = wr[0], w1 = wr[1];
        acc[0] = fmaf(sv, w0.x, acc[0]); acc[1] = fmaf(sv, w0.y, acc[1]);
        acc[2] = fmaf(sv, w0.z, acc[2]); acc[3] = fmaf(sv, w0.w, acc[3]);
        acc[4] = fmaf(sv, w1.x, acc[4]); acc[5] = fmaf(sv, w1.y, acc[5]);
        acc[6] = fmaf(sv, w1.z, acc[6]); acc[7] = fmaf(sv, w1.w, acc[7]);
    }

    __shared__ float red[16][8][64];
    #pragma unroll
    for (int j = 0; j < 8; ++j) red[wv][j][lane] = acc[j];
    __syncthreads();

    if (tid < 512) {
        const int j = tid >> 6, b = tid & 63;
        float s = 0.f;
        #pragma unroll
        for (int w = 0; w < 16; ++w) s += red[w][j][b];
        postx[(c0 + j) * 64 + b] = s + bo[c0 + j];
    }
}

// ---------------------------------------------------------------------------
// Kernel 5: dual LayerNorm (R8 version)
// ---------------------------------------------------------------------------
__global__ __launch_bounds__(256) void ln_kernel(
    const float* __restrict__ seq, const float* __restrict__ cand_s,
    const float* __restrict__ postx, const float* __restrict__ gamma,
    const float* __restrict__ beta, float* __restrict__ out)
{
    const int b   = blockIdx.x;
    const int tid = threadIdx.x;
    float x1[4], x2[4];
    float s1 = 0.f, q1 = 0.f, s2 = 0.f, q2 = 0.f;

    #pragma unroll
    for (int i = 0; i < 4; ++i) {
        int c = tid + i * 256;
        float px = postx[c * 64 + b];
        float sv = seq[b * HID + c];
        float cd = cand_s[c * 64 + b];
        float a = sv + px, d = px + cd;
        x1[i] = a; x2[i] = d;
        s1 += a; q1 += a * a; s2 += d; q2 += d * d;
    }
    #pragma unroll
    for (int m = 1; m < 64; m <<= 1) {
        s1 += __shfl_xor(s1, m); q1 += __shfl_xor(q1, m);
        s2 += __shfl_xor(s2, m); q2 += __shfl_xor(q2, m);
    }
    __shared__ float rsm[4][4];
    const int wv = tid >> 6, lane = tid & 63;
    if (lane == 0) { rsm[wv][0] = s1; rsm[wv][1] = q1; rsm[wv][2] = s2; rsm[wv][3] = q2; }
    __syncthreads();

    float S1 = rsm[0][0] + rsm[1][0] + rsm[2][0] + rsm[3][0];
    float Q1 = rsm[0][1] + rsm[1][1] + rsm[2][1] + rsm[3][1];
    float S2 = rsm[0][2] + rsm[1][2] + rsm[2][2] + rsm[3][2];
    float Q2 = rsm[0][3] + rsm[1][3] + rsm[2][3] + rsm[3][3];

    const float inv = 1.f / 1024.f;
    float mu1 = S1 * inv, v1 = Q1 * inv - mu1 * mu1;
    float mu2 = S2 * inv, v2 = Q2 * inv - mu2 * mu2;
    float r1 = rsqrtf(v1 + 1e-5f);
    float r2 = rsqrtf(v2 + 1e-5f);

    #pragma unroll
    for (int i = 0; i < 4; ++i) {
        int c = tid + i * 256;
        float g = gamma[c], be = beta[c];
        out[b * HID + c]            = (x1[i] - mu1) * r1 * g + be;   // seq_out
        out[NB * HID + b * HID + c] = (x2[i] - mu2) * r2 * g + be;   // candidate_out
    }
}

// ---------------------------------------------------------------------------
extern "C" void kernel_launch(void* const* d_in, const int* in_sizes, int n_in,
                              void* d_out, int out_size, void* d_ws, size_t ws_size,
                              hipStream_t stream) {
    const float* seq      = (const float*)d_in[0];
    const float* cand     = (const float*)d_in[1];
    const float* k_cache  = (const float*)d_in[2];
    const float* v_cache  = (const float*)d_in[3];
    const int*   seqlens  = (const int*)  d_in[4];
    const float* Wqkv     = (const float*)d_in[5];
    const float* bqkv     = (const float*)d_in[6];
    const float* Wc       = (const float*)d_in[7];
    const float* bcv      = (const float*)d_in[8];
    const float* Wo       = (const float*)d_in[9];
    const float* bo       = (const float*)d_in[10];
    const float* gamma    = (const float*)d_in[11];
    const float* beta     = (const float*)d_in[12];
    float* out = (float*)d_out;

    float* ws     = (float*)d_ws;
    float* proj   = ws;                        // [4096][64] = 262144 f
    float* attn   = proj  + 4096 * 64;         // [1024][64] =  65536 f
    float* postx  = attn  + 1024 * 64;         // [1024][64] =  65536 f
    float* part   = postx + 1024 * 64;         // [8*1024][PS] = 557056 f
    // probe scratch (outputs discarded; keeps work deterministic)
    float* attn2  = part  + NCH * 1024 * PS;   //  65536 f
    float* postx2 = attn2 + 1024 * 64;         //  65536 f
    float* out2   = postx2 + 1024 * 64;        // 131072 f

    // ---- real pipeline (R8, best known: 149.5 us) ----
    proj_kernel      <<<256, 1024, 0, stream>>>(seq, cand, Wqkv, bqkv, Wc, bcv, proj);
    attn_part_kernel <<<NCH * 1024, 256, 0, stream>>>(proj, k_cache, v_cache, seqlens, part);
    attn_merge_kernel<<<NB * NHEAD, 64, 0, stream>>>(part, seqlens, attn);
    wo_kernel        <<<128, 1024, 0, stream>>>(attn, Wo, bo, postx);
    ln_kernel        <<<NB, 256, 0, stream>>>(seq, proj + 3072 * 64, postx, gamma, beta, out);

    // ---- probe: duplicate the small trio into scratch.
    // dur - 149.5 = (merge+wo+ln, warm) + 3*launch_overhead -> separates
    // hypothesis (a) proj-heavy (delta ~15) from (b) overhead-heavy (~34).
    attn_merge_kernel<<<NB * NHEAD, 64, 0, stream>>>(part, seqlens, attn2);
    wo_kernel        <<<128, 1024, 0, stream>>>(attn, Wo, bo, postx2);
    ln_kernel        <<<NB, 256, 0, stream>>>(seq, proj + 3072 * 64, postx, gamma, beta, out2);
}

// Round 11
// 136.399 us; speedup vs baseline: 1.2123x; 1.1976x over previous
//
#include <hip/hip_runtime.h>
#include <hip/hip_fp16.h>
#include <math.h>

// Problem constants
#define HID   1024
#define NHEAD 16
#define HD    64
#define NB    64
#define MAXS  2048
#define CHUNK 256
#define NCH   (MAXS / CHUNK)          // 8
#define PS    68                      // floats per (chunk,b,h) partial record

// Non-temporal float4 load: skips cache retention on the streamed-once KV
// read. Measured: KV stream 4.5 -> 6.4 TB/s (R5/R7/R8 triple).
typedef float f4v __attribute__((ext_vector_type(4)));
__device__ __forceinline__ float4 ntload4(const float* p) {
    f4v v = __builtin_nontemporal_load((const f4v*)p);
    return make_float4(v.x, v.y, v.z, v.w);
}

// ---------------------------------------------------------------------------
// Kernel 1: fused projections, LDS-STAGED W.
// R10 probe isolated proj at ~45 us (17x its 2.6 us memory roofline): the
// wave-uniform W loads go down the scalar/broadcast path (shallow queue, 64 B
// per request, ~900 cyc cold) and serialize. Fix: cooperative per-lane
// coalesced staging of the whole [1024][16] W tile into LDS (deep vmcnt
// queue, each line fetched once), then wave-uniform LDS broadcast reads
// (free). Compute skeleton + reduction unchanged from R1.
// ---------------------------------------------------------------------------
__global__ __launch_bounds__(1024) void proj_kernel(
    const float* __restrict__ seq, const float* __restrict__ cand,
    const float* __restrict__ Wqkv, const float* __restrict__ bqkv,
    const float* __restrict__ Wc,   const float* __restrict__ bcv,
    float* __restrict__ out /* [4096][64] col-major */)
{
    const int tid  = threadIdx.x;
    const int wv   = tid >> 6;
    const int lane = tid & 63;
    const int c0   = blockIdx.x * 16;
    const bool is_qkv = (c0 < 3072);
    const float* __restrict__ src  = is_qkv ? seq  : cand;
    const float* __restrict__ W    = is_qkv ? Wqkv : Wc;
    const float* __restrict__ bias = is_qkv ? bqkv : bcv;
    const int ldw = is_qkv ? 3072 : 1024;
    const int cb  = is_qkv ? c0 : (c0 - 3072);

    __shared__ float wt[1024][16];      // 64 KB staged W tile
    __shared__ float red[16][16][64];   // 64 KB reduction buffer

    // ---- stage W tile: per-lane coalesced (16 threads = 64 B row segment) ----
    {
        const int r0 = tid >> 4;        // 0..63
        const int cc = tid & 15;
        #pragma unroll
        for (int i = 0; i < 16; ++i) {
            const int r = i * 64 + r0;
            wt[r][cc] = W[(size_t)r * ldw + cb + cc];
        }
    }
    __syncthreads();

    // ---- compute: wave wv owns k-rows [wv*64, +63]; lane = batch ----
    const int k0 = wv * 64;
    float acc[16];
    #pragma unroll
    for (int j = 0; j < 16; ++j) acc[j] = 0.f;

    const float4* sp = (const float4*)(src + lane * HID + k0);
    for (int kc = 0; kc < 16; ++kc) {
        float4 s4 = sp[kc];
        #pragma unroll
        for (int t = 0; t < 4; ++t) {
            float sv = (t == 0) ? s4.x : (t == 1) ? s4.y : (t == 2) ? s4.z : s4.w;
            const float4* wr = (const float4*)&wt[k0 + kc * 4 + t][0];   // uniform -> broadcast
            #pragma unroll
            for (int j = 0; j < 4; ++j) {
                float4 w4 = wr[j];
                acc[4*j+0] = fmaf(sv, w4.x, acc[4*j+0]);
                acc[4*j+1] = fmaf(sv, w4.y, acc[4*j+1]);
                acc[4*j+2] = fmaf(sv, w4.z, acc[4*j+2]);
                acc[4*j+3] = fmaf(sv, w4.w, acc[4*j+3]);
            }
        }
    }

    #pragma unroll
    for (int j = 0; j < 16; ++j) red[wv][j][lane] = acc[j];
    __syncthreads();

    {
        const int j = tid >> 6, b = tid & 63;
        float s = 0.f;
        #pragma unroll
        for (int w = 0; w < 16; ++w) s += red[w][j][b];
        out[(c0 + j) * 64 + b] = s + bias[cb + j];
    }
}

// ---------------------------------------------------------------------------
// Kernel 2: TWO-PHASE chunked attention partials, nt loads (R8, unchanged —
// measured 6.4 TB/s, read roofline).
// ---------------------------------------------------------------------------
__global__ __launch_bounds__(256) void attn_part_kernel(
    const float* __restrict__ proj, const float* __restrict__ k_cache,
    const float* __restrict__ v_cache, const int* __restrict__ seqlens,
    float* __restrict__ part)
{
    const int idx = blockIdx.x;
    const int c  = idx >> 10;
    const int bh = idx & 1023;
    const int b  = bh >> 4;
    const int h  = bh & 15;
    const int L  = seqlens[b];
    const int s0 = c << 8;
    if (s0 > L) return;

    const int tid = threadIdx.x;
    const int grp = tid >> 4;
    const int gl  = tid & 15;
    const bool has_new = (L < s0 + CHUNK);

    __shared__ float lq[64], lk[64], lv[64];
    __shared__ float sm_m[16], sm_l[16];
    __shared__ float sm_o[16][64];

    if (tid < 64) {
        lq[tid] = proj[(h * 192 + tid) * 64 + b];
    } else if (tid < 128) {
        if (has_new) {
            int d = tid - 64;
            float kr = proj[(h * 192 + 64 + d) * 64 + b];
            float ss = kr * kr;
            #pragma unroll
            for (int m = 1; m < 64; m <<= 1) ss += __shfl_xor(ss, m);
            float kn = kr / sqrtf(ss);
            lk[d] = __half2float(__float2half_rn(kn));
        }
    } else if (tid < 192) {
        if (has_new) {
            int d = tid - 128;
            lv[d] = proj[(h * 192 + 128 + d) * 64 + b];
        }
    }
    __syncthreads();

    const float4 q4 = ((const float4*)lq)[gl];
    const size_t base0 = (((size_t)b * MAXS) * NHEAD + h) * HD;

    float sc[16];
    float m, l;
    float4 o = make_float4(0.f, 0.f, 0.f, 0.f);

    if (!has_new) {
        #pragma unroll
        for (int t = 0; t < 16; ++t) {
            const int s = s0 + grp + t * 16;
            float4 k4 = ntload4(k_cache + base0 + (size_t)s * (NHEAD * HD) + gl * 4);
            float d = fmaf(k4.x, q4.x, fmaf(k4.y, q4.y, fmaf(k4.z, q4.z, k4.w * q4.w)));
            d += __shfl_xor(d, 1); d += __shfl_xor(d, 2);
            d += __shfl_xor(d, 4); d += __shfl_xor(d, 8);
            sc[t] = d;
        }
        m = sc[0];
        #pragma unroll
        for (int t = 1; t < 16; ++t) m = fmaxf(m, sc[t]);
        l = 0.f;
        #pragma unroll
        for (int t = 0; t < 16; ++t) { float p = __expf(sc[t] - m); sc[t] = p; l += p; }
        #pragma unroll
        for (int t = 0; t < 16; ++t) {
            const int s = s0 + grp + t * 16;
            float4 v4 = ntload4(v_cache + base0 + (size_t)s * (NHEAD * HD) + gl * 4);
            o.x = fmaf(sc[t], v4.x, o.x);
            o.y = fmaf(sc[t], v4.y, o.y);
            o.z = fmaf(sc[t], v4.z, o.z);
            o.w = fmaf(sc[t], v4.w, o.w);
        }
    } else {
        #pragma unroll
        for (int t = 0; t < 16; ++t) {
            const int s = s0 + grp + t * 16;
            float4 k4 = make_float4(0.f, 0.f, 0.f, 0.f);
            if (s < L)       k4 = ntload4(k_cache + base0 + (size_t)s * (NHEAD * HD) + gl * 4);
            else if (s == L) k4 = ((const float4*)lk)[gl];
            float d = fmaf(k4.x, q4.x, fmaf(k4.y, q4.y, fmaf(k4.z, q4.z, k4.w * q4.w)));
            d += __shfl_xor(d, 1); d += __shfl_xor(d, 2);
            d += __shfl_xor(d, 4); d += __shfl_xor(d, 8);
            sc[t] = (s <= L) ? d : -INFINITY;
        }
        m = sc[0];
        #pragma unroll
        for (int t = 1; t < 16; ++t) m = fmaxf(m, sc[t]);
        const float mm = (m == -INFINITY) ? 0.f : m;   // NaN guard (empty group)
        l = 0.f;
        #pragma unroll
        for (int t = 0; t < 16; ++t) { float p = __expf(sc[t] - mm); sc[t] = p; l += p; }
        #pragma unroll
        for (int t = 0; t < 16; ++t) {
            const int s = s0 + grp + t * 16;
            float4 v4 = make_float4(0.f, 0.f, 0.f, 0.f);
            if (s < L)       v4 = ntload4(v_cache + base0 + (size_t)s * (NHEAD * HD) + gl * 4);
            else if (s == L) v4 = ((const float4*)lv)[gl];
            o.x = fmaf(sc[t], v4.x, o.x);
            o.y = fmaf(sc[t], v4.y, o.y);
            o.z = fmaf(sc[t], v4.z, o.z);
            o.w = fmaf(sc[t], v4.w, o.w);
        }
    }

    if (gl == 0) { sm_m[grp] = m; sm_l[grp] = l; }
    ((float4*)sm_o[grp])[gl] = o;
    __syncthreads();

    if (tid < 64) {
        float M = -INFINITY;
        #pragma unroll
        for (int g = 0; g < 16; ++g) M = fmaxf(M, sm_m[g]);
        float li = 0.f, oi = 0.f;
        #pragma unroll
        for (int g = 0; g < 16; ++g) {
            float w = __expf(sm_m[g] - M);
            li += w * sm_l[g];
            oi += w * sm_o[g][tid];
        }
        float* pb = part + (size_t)(c * 1024 + bh) * PS;
        pb[tid] = oi;
        if (tid == 0) { pb[64] = M; pb[65] = li; }
    }
}

// ---------------------------------------------------------------------------
// Kernel 3: merge <=8 chunk partials per (b,h). 1024 blocks x 64 threads.
// ---------------------------------------------------------------------------
__global__ __launch_bounds__(64) void attn_merge_kernel(
    const float* __restrict__ part, const int* __restrict__ seqlens,
    float* __restrict__ attn_out /* [1024][64] col-major */)
{
    const int bh = blockIdx.x;
    const int b  = bh >> 4;
    const int h  = bh & 15;
    const int d  = threadIdx.x;
    const int nch = (seqlens[b] >> 8) + 1;

    float M = -INFINITY, l = 0.f, o = 0.f;
    for (int c = 0; c < nch; ++c) {
        const float* pb = part + (size_t)(c * 1024 + bh) * PS;
        float mc = pb[64], lc = pb[65];
        float Mn = fmaxf(M, mc);
        float f = __expf(M - Mn);
        float w = __expf(mc - Mn);
        o = o * f + w * pb[d];
        l = l * f + w * lc;
        M = Mn;
    }
    attn_out[(h * 64 + d) * 64 + b] = o / l;
}

// ---------------------------------------------------------------------------
// Kernel 4: postx = attn @ Wo + bo (R8 version — Wo read exactly once)
// ---------------------------------------------------------------------------
__global__ __launch_bounds__(1024) void wo_kernel(
    const float* __restrict__ attn_s, const float* __restrict__ Wo,
    const float* __restrict__ bo, float* __restrict__ postx /* [1024][64] */)
{
    const int tid  = threadIdx.x;
    const int wv   = __builtin_amdgcn_readfirstlane(tid >> 6);
    const int lane = tid & 63;
    const int c0   = blockIdx.x * 8;
    const int k0   = wv * 64;

    float acc[8];
    #pragma unroll
    for (int j = 0; j < 8; ++j) acc[j] = 0.f;

    for (int k = 0; k < 64; ++k) {
        float sv = attn_s[(k0 + k) * 64 + lane];
        const float4* wr = (const float4*)(Wo + (size_t)(k0 + k) * 1024 + c0);
        float4 w0 = wr[0], w1 = wr[1];
        acc[0] = fmaf(sv, w0.x, acc[0]); acc[1] = fmaf(sv, w0.y, acc[1]);
        acc[2] = fmaf(sv, w0.z, acc[2]); acc[3] = fmaf(sv, w0.w, acc[3]);
        acc[4] = fmaf(sv, w1.x, acc[4]); acc[5] = fmaf(sv, w1.y, acc[5]);
        acc[6] = fmaf(sv, w1.z, acc[6]); acc[7] = fmaf(sv, w1.w, acc[7]);
    }

    __shared__ float red[16][8][64];
    #pragma unroll
    for (int j = 0; j < 8; ++j) red[wv][j][lane] = acc[j];
    __syncthreads();

    if (tid < 512) {
        const int j = tid >> 6, b = tid & 63;
        float s = 0.f;
        #pragma unroll
        for (int w = 0; w < 16; ++w) s += red[w][j][b];
        postx[(c0 + j) * 64 + b] = s + bo[c0 + j];
    }
}

// ---------------------------------------------------------------------------
// Kernel 5: dual LayerNorm (R8 version)
// ---------------------------------------------------------------------------
__global__ __launch_bounds__(256) void ln_kernel(
    const float* __restrict__ seq, const float* __restrict__ cand_s,
    const float* __restrict__ postx, const float* __restrict__ gamma,
    const float* __restrict__ beta, float* __restrict__ out)
{
    const int b   = blockIdx.x;
    const int tid = threadIdx.x;
    float x1[4], x2[4];
    float s1 = 0.f, q1 = 0.f, s2 = 0.f, q2 = 0.f;

    #pragma unroll
    for (int i = 0; i < 4; ++i) {
        int c = tid + i * 256;
        float px = postx[c * 64 + b];
        float sv = seq[b * HID + c];
        float cd = cand_s[c * 64 + b];
        float a = sv + px, d = px + cd;
        x1[i] = a; x2[i] = d;
        s1 += a; q1 += a * a; s2 += d; q2 += d * d;
    }
    #pragma unroll
    for (int m = 1; m < 64; m <<= 1) {
        s1 += __shfl_xor(s1, m); q1 += __shfl_xor(q1, m);
        s2 += __shfl_xor(s2, m); q2 += __shfl_xor(q2, m);
    }
    __shared__ float rsm[4][4];
    const int wv = tid >> 6, lane = tid & 63;
    if (lane == 0) { rsm[wv][0] = s1; rsm[wv][1] = q1; rsm[wv][2] = s2; rsm[wv][3] = q2; }
    __syncthreads();

    float S1 = rsm[0][0] + rsm[1][0] + rsm[2][0] + rsm[3][0];
    float Q1 = rsm[0][1] + rsm[1][1] + rsm[2][1] + rsm[3][1];
    float S2 = rsm[0][2] + rsm[1][2] + rsm[2][2] + rsm[3][2];
    float Q2 = rsm[0][3] + rsm[1][3] + rsm[2][3] + rsm[3][3];

    const float inv = 1.f / 1024.f;
    float mu1 = S1 * inv, v1 = Q1 * inv - mu1 * mu1;
    float mu2 = S2 * inv, v2 = Q2 * inv - mu2 * mu2;
    float r1 = rsqrtf(v1 + 1e-5f);
    float r2 = rsqrtf(v2 + 1e-5f);

    #pragma unroll
    for (int i = 0; i < 4; ++i) {
        int c = tid + i * 256;
        float g = gamma[c], be = beta[c];
        out[b * HID + c]            = (x1[i] - mu1) * r1 * g + be;   // seq_out
        out[NB * HID + b * HID + c] = (x2[i] - mu2) * r2 * g + be;   // candidate_out
    }
}

// ---------------------------------------------------------------------------
extern "C" void kernel_launch(void* const* d_in, const int* in_sizes, int n_in,
                              void* d_out, int out_size, void* d_ws, size_t ws_size,
                              hipStream_t stream) {
    const float* seq      = (const float*)d_in[0];
    const float* cand     = (const float*)d_in[1];
    const float* k_cache  = (const float*)d_in[2];
    const float* v_cache  = (const float*)d_in[3];
    const int*   seqlens  = (const int*)  d_in[4];
    const float* Wqkv     = (const float*)d_in[5];
    const float* bqkv     = (const float*)d_in[6];
    const float* Wc       = (const float*)d_in[7];
    const float* bcv      = (const float*)d_in[8];
    const float* Wo       = (const float*)d_in[9];
    const float* bo       = (const float*)d_in[10];
    const float* gamma    = (const float*)d_in[11];
    const float* beta     = (const float*)d_in[12];
    float* out = (float*)d_out;

    float* ws    = (float*)d_ws;
    float* proj  = ws;                         // [4096][64] = 262144 f
    float* attn  = proj  + 4096 * 64;          // [1024][64] =  65536 f
    float* postx = attn  + 1024 * 64;          // [1024][64] =  65536 f
    float* part  = postx + 1024 * 64;          // [8*1024][PS] = 557056 f

    proj_kernel      <<<256, 1024, 0, stream>>>(seq, cand, Wqkv, bqkv, Wc, bcv, proj);
    attn_part_kernel <<<NCH * 1024, 256, 0, stream>>>(proj, k_cache, v_cache, seqlens, part);
    attn_merge_kernel<<<NB * NHEAD, 64, 0, stream>>>(part, seqlens, attn);
    wo_kernel        <<<128, 1024, 0, stream>>>(attn, Wo, bo, postx);
    ln_kernel        <<<NB, 256, 0, stream>>>(seq, proj + 3072 * 64, postx, gamma, beta, out);
}

// Round 12
// 135.098 us; speedup vs baseline: 1.2240x; 1.0096x over previous
//
#include <hip/hip_runtime.h>
#include <hip/hip_fp16.h>
#include <math.h>

// Problem constants
#define HID   1024
#define NHEAD 16
#define HD    64
#define NB    64
#define MAXS  2048
#define CHUNK 256
#define NCH   (MAXS / CHUNK)          // 8
#define PS    68                      // floats per (chunk,b,h) partial record

// Non-temporal float4 load: skips cache retention on the streamed-once KV
// read. Measured: KV stream 4.5 -> 6.4 TB/s (R5/R7/R8 triple).
typedef float f4v __attribute__((ext_vector_type(4)));
__device__ __forceinline__ float4 ntload4(const float* p) {
    f4v v = __builtin_nontemporal_load((const f4v*)p);
    return make_float4(v.x, v.y, v.z, v.w);
}

// ---------------------------------------------------------------------------
// Kernel 1: fused projections, WAVE-INDEPENDENT LDS staging.
// R11 kept a block-wide __syncthreads between W-tile staging and compute; at
// 1 block/CU (128 KB LDS) that serializes the phases: stage(~15-20us cold
// sparse) + compute(~10us). Fix: wave wv stages exactly its own k-quadrant
// (rows wv*64..+63, float4 loads) and computes on it with NO block barrier —
// same-wave DS ops are in-order, so write->read within the wave is safe.
// Waves pipeline independently: one wave's HBM latency hides under another's
// FMA/LDS work. red-phase reduction keeps its __syncthreads.
// ---------------------------------------------------------------------------
__global__ __launch_bounds__(1024) void proj_kernel(
    const float* __restrict__ seq, const float* __restrict__ cand,
    const float* __restrict__ Wqkv, const float* __restrict__ bqkv,
    const float* __restrict__ Wc,   const float* __restrict__ bcv,
    float* __restrict__ out /* [4096][64] col-major */)
{
    const int tid  = threadIdx.x;
    const int wv   = tid >> 6;
    const int lane = tid & 63;
    const int c0   = blockIdx.x * 16;
    const bool is_qkv = (c0 < 3072);
    const float* __restrict__ src  = is_qkv ? seq  : cand;
    const float* __restrict__ W    = is_qkv ? Wqkv : Wc;
    const float* __restrict__ bias = is_qkv ? bqkv : bcv;
    const int ldw = is_qkv ? 3072 : 1024;
    const int cb  = is_qkv ? c0 : (c0 - 3072);
    const int k0  = wv * 64;

    __shared__ float wt[1024][16];      // 64 KB staged W tile (per-wave quadrants)
    __shared__ float red[16][16][64];   // 64 KB reduction buffer

    // ---- stage OWN quadrant: lane -> (row k0+(lane>>2)+16i, colquad (lane&3)*4)
    {
        const int r  = k0 + (lane >> 2);
        const int cq = (lane & 3) * 4;
        #pragma unroll
        for (int i = 0; i < 4; ++i) {
            *(float4*)&wt[r + i * 16][cq] =
                *(const float4*)&W[(size_t)(r + i * 16) * ldw + cb + cq];
        }
    }
    __builtin_amdgcn_wave_barrier();    // compiler ordering fence (no-op instr);
                                        // same-wave DS queue is in-order in HW.

    // ---- compute: wave wv owns k-rows [k0, k0+63]; lane = batch ----
    float acc[16];
    #pragma unroll
    for (int j = 0; j < 16; ++j) acc[j] = 0.f;

    const float4* sp = (const float4*)(src + lane * HID + k0);
    for (int kc = 0; kc < 16; ++kc) {
        float4 s4 = sp[kc];
        #pragma unroll
        for (int t = 0; t < 4; ++t) {
            float sv = (t == 0) ? s4.x : (t == 1) ? s4.y : (t == 2) ? s4.z : s4.w;
            const float4* wr = (const float4*)&wt[k0 + kc * 4 + t][0];   // own quadrant
            #pragma unroll
            for (int j = 0; j < 4; ++j) {
                float4 w4 = wr[j];
                acc[4*j+0] = fmaf(sv, w4.x, acc[4*j+0]);
                acc[4*j+1] = fmaf(sv, w4.y, acc[4*j+1]);
                acc[4*j+2] = fmaf(sv, w4.z, acc[4*j+2]);
                acc[4*j+3] = fmaf(sv, w4.w, acc[4*j+3]);
            }
        }
    }

    #pragma unroll
    for (int j = 0; j < 16; ++j) red[wv][j][lane] = acc[j];
    __syncthreads();

    {
        const int j = tid >> 6, b = tid & 63;
        float s = 0.f;
        #pragma unroll
        for (int w = 0; w < 16; ++w) s += red[w][j][b];
        out[(c0 + j) * 64 + b] = s + bias[cb + j];
    }
}

// ---------------------------------------------------------------------------
// Kernel 2: TWO-PHASE chunked attention partials, nt loads (R8, unchanged —
// measured 6.4 TB/s, read roofline).
// ---------------------------------------------------------------------------
__global__ __launch_bounds__(256) void attn_part_kernel(
    const float* __restrict__ proj, const float* __restrict__ k_cache,
    const float* __restrict__ v_cache, const int* __restrict__ seqlens,
    float* __restrict__ part)
{
    const int idx = blockIdx.x;
    const int c  = idx >> 10;
    const int bh = idx & 1023;
    const int b  = bh >> 4;
    const int h  = bh & 15;
    const int L  = seqlens[b];
    const int s0 = c << 8;
    if (s0 > L) return;

    const int tid = threadIdx.x;
    const int grp = tid >> 4;
    const int gl  = tid & 15;
    const bool has_new = (L < s0 + CHUNK);

    __shared__ float lq[64], lk[64], lv[64];
    __shared__ float sm_m[16], sm_l[16];
    __shared__ float sm_o[16][64];

    if (tid < 64) {
        lq[tid] = proj[(h * 192 + tid) * 64 + b];
    } else if (tid < 128) {
        if (has_new) {
            int d = tid - 64;
            float kr = proj[(h * 192 + 64 + d) * 64 + b];
            float ss = kr * kr;
            #pragma unroll
            for (int m = 1; m < 64; m <<= 1) ss += __shfl_xor(ss, m);
            float kn = kr / sqrtf(ss);
            lk[d] = __half2float(__float2half_rn(kn));
        }
    } else if (tid < 192) {
        if (has_new) {
            int d = tid - 128;
            lv[d] = proj[(h * 192 + 128 + d) * 64 + b];
        }
    }
    __syncthreads();

    const float4 q4 = ((const float4*)lq)[gl];
    const size_t base0 = (((size_t)b * MAXS) * NHEAD + h) * HD;

    float sc[16];
    float m, l;
    float4 o = make_float4(0.f, 0.f, 0.f, 0.f);

    if (!has_new) {
        #pragma unroll
        for (int t = 0; t < 16; ++t) {
            const int s = s0 + grp + t * 16;
            float4 k4 = ntload4(k_cache + base0 + (size_t)s * (NHEAD * HD) + gl * 4);
            float d = fmaf(k4.x, q4.x, fmaf(k4.y, q4.y, fmaf(k4.z, q4.z, k4.w * q4.w)));
            d += __shfl_xor(d, 1); d += __shfl_xor(d, 2);
            d += __shfl_xor(d, 4); d += __shfl_xor(d, 8);
            sc[t] = d;
        }
        m = sc[0];
        #pragma unroll
        for (int t = 1; t < 16; ++t) m = fmaxf(m, sc[t]);
        l = 0.f;
        #pragma unroll
        for (int t = 0; t < 16; ++t) { float p = __expf(sc[t] - m); sc[t] = p; l += p; }
        #pragma unroll
        for (int t = 0; t < 16; ++t) {
            const int s = s0 + grp + t * 16;
            float4 v4 = ntload4(v_cache + base0 + (size_t)s * (NHEAD * HD) + gl * 4);
            o.x = fmaf(sc[t], v4.x, o.x);
            o.y = fmaf(sc[t], v4.y, o.y);
            o.z = fmaf(sc[t], v4.z, o.z);
            o.w = fmaf(sc[t], v4.w, o.w);
        }
    } else {
        #pragma unroll
        for (int t = 0; t < 16; ++t) {
            const int s = s0 + grp + t * 16;
            float4 k4 = make_float4(0.f, 0.f, 0.f, 0.f);
            if (s < L)       k4 = ntload4(k_cache + base0 + (size_t)s * (NHEAD * HD) + gl * 4);
            else if (s == L) k4 = ((const float4*)lk)[gl];
            float d = fmaf(k4.x, q4.x, fmaf(k4.y, q4.y, fmaf(k4.z, q4.z, k4.w * q4.w)));
            d += __shfl_xor(d, 1); d += __shfl_xor(d, 2);
            d += __shfl_xor(d, 4); d += __shfl_xor(d, 8);
            sc[t] = (s <= L) ? d : -INFINITY;
        }
        m = sc[0];
        #pragma unroll
        for (int t = 1; t < 16; ++t) m = fmaxf(m, sc[t]);
        const float mm = (m == -INFINITY) ? 0.f : m;   // NaN guard (empty group)
        l = 0.f;
        #pragma unroll
        for (int t = 0; t < 16; ++t) { float p = __expf(sc[t] - mm); sc[t] = p; l += p; }
        #pragma unroll
        for (int t = 0; t < 16; ++t) {
            const int s = s0 + grp + t * 16;
            float4 v4 = make_float4(0.f, 0.f, 0.f, 0.f);
            if (s < L)       v4 = ntload4(v_cache + base0 + (size_t)s * (NHEAD * HD) + gl * 4);
            else if (s == L) v4 = ((const float4*)lv)[gl];
            o.x = fmaf(sc[t], v4.x, o.x);
            o.y = fmaf(sc[t], v4.y, o.y);
            o.z = fmaf(sc[t], v4.z, o.z);
            o.w = fmaf(sc[t], v4.w, o.w);
        }
    }

    if (gl == 0) { sm_m[grp] = m; sm_l[grp] = l; }
    ((float4*)sm_o[grp])[gl] = o;
    __syncthreads();

    if (tid < 64) {
        float M = -INFINITY;
        #pragma unroll
        for (int g = 0; g < 16; ++g) M = fmaxf(M, sm_m[g]);
        float li = 0.f, oi = 0.f;
        #pragma unroll
        for (int g = 0; g < 16; ++g) {
            float w = __expf(sm_m[g] - M);
            li += w * sm_l[g];
            oi += w * sm_o[g][tid];
        }
        float* pb = part + (size_t)(c * 1024 + bh) * PS;
        pb[tid] = oi;
        if (tid == 0) { pb[64] = M; pb[65] = li; }
    }
}

// ---------------------------------------------------------------------------
// Kernel 3: merge <=8 chunk partials per (b,h). 1024 blocks x 64 threads.
// ---------------------------------------------------------------------------
__global__ __launch_bounds__(64) void attn_merge_kernel(
    const float* __restrict__ part, const int* __restrict__ seqlens,
    float* __restrict__ attn_out /* [1024][64] col-major */)
{
    const int bh = blockIdx.x;
    const int b  = bh >> 4;
    const int h  = bh & 15;
    const int d  = threadIdx.x;
    const int nch = (seqlens[b] >> 8) + 1;

    float M = -INFINITY, l = 0.f, o = 0.f;
    for (int c = 0; c < nch; ++c) {
        const float* pb = part + (size_t)(c * 1024 + bh) * PS;
        float mc = pb[64], lc = pb[65];
        float Mn = fmaxf(M, mc);
        float f = __expf(M - Mn);
        float w = __expf(mc - Mn);
        o = o * f + w * pb[d];
        l = l * f + w * lc;
        M = Mn;
    }
    attn_out[(h * 64 + d) * 64 + b] = o / l;
}

// ---------------------------------------------------------------------------
// Kernel 4: postx = attn @ Wo + bo (R8 version — Wo read exactly once)
// ---------------------------------------------------------------------------
__global__ __launch_bounds__(1024) void wo_kernel(
    const float* __restrict__ attn_s, const float* __restrict__ Wo,
    const float* __restrict__ bo, float* __restrict__ postx /* [1024][64] */)
{
    const int tid  = threadIdx.x;
    const int wv   = __builtin_amdgcn_readfirstlane(tid >> 6);
    const int lane = tid & 63;
    const int c0   = blockIdx.x * 8;
    const int k0   = wv * 64;

    float acc[8];
    #pragma unroll
    for (int j = 0; j < 8; ++j) acc[j] = 0.f;

    for (int k = 0; k < 64; ++k) {
        float sv = attn_s[(k0 + k) * 64 + lane];
        const float4* wr = (const float4*)(Wo + (size_t)(k0 + k) * 1024 + c0);
        float4 w0 = wr[0], w1 = wr[1];
        acc[0] = fmaf(sv, w0.x, acc[0]); acc[1] = fmaf(sv, w0.y, acc[1]);
        acc[2] = fmaf(sv, w0.z, acc[2]); acc[3] = fmaf(sv, w0.w, acc[3]);
        acc[4] = fmaf(sv, w1.x, acc[4]); acc[5] = fmaf(sv, w1.y, acc[5]);
        acc[6] = fmaf(sv, w1.z, acc[6]); acc[7] = fmaf(sv, w1.w, acc[7]);
    }

    __shared__ float red[16][8][64];
    #pragma unroll
    for (int j = 0; j < 8; ++j) red[wv][j][lane] = acc[j];
    __syncthreads();

    if (tid < 512) {
        const int j = tid >> 6, b = tid & 63;
        float s = 0.f;
        #pragma unroll
        for (int w = 0; w < 16; ++w) s += red[w][j][b];
        postx[(c0 + j) * 64 + b] = s + bo[c0 + j];
    }
}

// ---------------------------------------------------------------------------
// Kernel 5: dual LayerNorm (R8 version)
// ---------------------------------------------------------------------------
__global__ __launch_bounds__(256) void ln_kernel(
    const float* __restrict__ seq, const float* __restrict__ cand_s,
    const float* __restrict__ postx, const float* __restrict__ gamma,
    const float* __restrict__ beta, float* __restrict__ out)
{
    const int b   = blockIdx.x;
    const int tid = threadIdx.x;
    float x1[4], x2[4];
    float s1 = 0.f, q1 = 0.f, s2 = 0.f, q2 = 0.f;

    #pragma unroll
    for (int i = 0; i < 4; ++i) {
        int c = tid + i * 256;
        float px = postx[c * 64 + b];
        float sv = seq[b * HID + c];
        float cd = cand_s[c * 64 + b];
        float a = sv + px, d = px + cd;
        x1[i] = a; x2[i] = d;
        s1 += a; q1 += a * a; s2 += d; q2 += d * d;
    }
    #pragma unroll
    for (int m = 1; m < 64; m <<= 1) {
        s1 += __shfl_xor(s1, m); q1 += __shfl_xor(q1, m);
        s2 += __shfl_xor(s2, m); q2 += __shfl_xor(q2, m);
    }
    __shared__ float rsm[4][4];
    const int wv = tid >> 6, lane = tid & 63;
    if (lane == 0) { rsm[wv][0] = s1; rsm[wv][1] = q1; rsm[wv][2] = s2; rsm[wv][3] = q2; }
    __syncthreads();

    float S1 = rsm[0][0] + rsm[1][0] + rsm[2][0] + rsm[3][0];
    float Q1 = rsm[0][1] + rsm[1][1] + rsm[2][1] + rsm[3][1];
    float S2 = rsm[0][2] + rsm[1][2] + rsm[2][2] + rsm[3][2];
    float Q2 = rsm[0][3] + rsm[1][3] + rsm[2][3] + rsm[3][3];

    const float inv = 1.f / 1024.f;
    float mu1 = S1 * inv, v1 = Q1 * inv - mu1 * mu1;
    float mu2 = S2 * inv, v2 = Q2 * inv - mu2 * mu2;
    float r1 = rsqrtf(v1 + 1e-5f);
    float r2 = rsqrtf(v2 + 1e-5f);

    #pragma unroll
    for (int i = 0; i < 4; ++i) {
        int c = tid + i * 256;
        float g = gamma[c], be = beta[c];
        out[b * HID + c]            = (x1[i] - mu1) * r1 * g + be;   // seq_out
        out[NB * HID + b * HID + c] = (x2[i] - mu2) * r2 * g + be;   // candidate_out
    }
}

// ---------------------------------------------------------------------------
extern "C" void kernel_launch(void* const* d_in, const int* in_sizes, int n_in,
                              void* d_out, int out_size, void* d_ws, size_t ws_size,
                              hipStream_t stream) {
    const float* seq      = (const float*)d_in[0];
    const float* cand     = (const float*)d_in[1];
    const float* k_cache  = (const float*)d_in[2];
    const float* v_cache  = (const float*)d_in[3];
    const int*   seqlens  = (const int*)  d_in[4];
    const float* Wqkv     = (const float*)d_in[5];
    const float* bqkv     = (const float*)d_in[6];
    const float* Wc       = (const float*)d_in[7];
    const float* bcv      = (const float*)d_in[8];
    const float* Wo       = (const float*)d_in[9];
    const float* bo       = (const float*)d_in[10];
    const float* gamma    = (const float*)d_in[11];
    const float* beta     = (const float*)d_in[12];
    float* out = (float*)d_out;

    float* ws    = (float*)d_ws;
    float* proj  = ws;                         // [4096][64] = 262144 f
    float* attn  = proj  + 4096 * 64;          // [1024][64] =  65536 f
    float* postx = attn  + 1024 * 64;          // [1024][64] =  65536 f
    float* part  = postx + 1024 * 64;          // [8*1024][PS] = 557056 f

    proj_kernel      <<<256, 1024, 0, stream>>>(seq, cand, Wqkv, bqkv, Wc, bcv, proj);
    attn_part_kernel <<<NCH * 1024, 256, 0, stream>>>(proj, k_cache, v_cache, seqlens, part);
    attn_merge_kernel<<<NB * NHEAD, 64, 0, stream>>>(part, seqlens, attn);
    wo_kernel        <<<128, 1024, 0, stream>>>(attn, Wo, bo, postx);
    ln_kernel        <<<NB, 256, 0, stream>>>(seq, proj + 3072 * 64, postx, gamma, beta, out);
}